// Round 1
// baseline (770.827 us; speedup 1.0000x reference)
//
#include <hip/hip_runtime.h>
#include <stdint.h>

typedef __attribute__((ext_vector_type(8))) short short8;
typedef __attribute__((ext_vector_type(4))) float floatx4;

#define MFMA16(a, b, c) __builtin_amdgcn_mfma_f32_16x16x32_bf16(a, b, c, 0, 0, 0)

__device__ __forceinline__ unsigned short f2bf(float x) {
    unsigned u = __builtin_bit_cast(unsigned, x);
    u = (u + 0x7fffu + ((u >> 16) & 1u)) >> 16;  // RNE
    return (unsigned short)u;
}

// XOR-swizzled LDS index for the 128x128 bf16 activation buffer.
// 16B chunks permuted within each 256B row: keeps b128 A-frag reads and
// b16 C-layout writes bank-balanced (stride-256B unswizzled = 16-way).
__device__ __forceinline__ int hidx(int row, int col) {
    return row * 128 + (((col >> 3) ^ (row & 15)) << 3) + (col & 7);
}

// Grid: (2040, 3). y=0: fwd MLP, y=1: bwd MLP, y=2 (x<1024): init MLP.
// Main path: each WG = 4 waves; 4 tiles of 128 rows each (grid-stride).
// N-split: wave w owns hidden cols [32w, 32w+32) for layers 1-2, so its
// W1/W2 B-frags stay in registers for the whole kernel. Layer 3 is M-split
// (wave w owns rows [32w,32w+32)) with W3 B-frags (N-padded 2->16) in regs.
__global__ __launch_bounds__(256, 4)
void NeuralNet_37615323578557_kernel(
        const float* __restrict__ x, const float* __restrict__ t,
        const float* __restrict__ fW1, const float* __restrict__ fb1,
        const float* __restrict__ fW2, const float* __restrict__ fb2,
        const float* __restrict__ fW3, const float* __restrict__ fb3,
        const float* __restrict__ gW1, const float* __restrict__ gb1,
        const float* __restrict__ gW2, const float* __restrict__ gb2,
        const float* __restrict__ gW3, const float* __restrict__ gb3,
        const float* __restrict__ iW1, const float* __restrict__ ib1,
        const float* __restrict__ iW2, const float* __restrict__ ib2,
        const float* __restrict__ iW3, const float* __restrict__ ib3,
        float* __restrict__ out) {
    __shared__ unsigned short hbuf[128 * 128];  // 32 KB, h1 then h2
    __shared__ unsigned short fbuf[128 * 8];    // 2 KB feature staging

    const int tid  = threadIdx.x;
    const int lane = tid & 63;
    const int w    = tid >> 6;      // wave 0..3
    const int c    = lane & 15;     // MFMA low index (m for A, n for B/C)
    const int q    = lane >> 4;     // MFMA quad

    // ---------------- init-MLP path (tiny, fp32 VALU) ----------------
    if (blockIdx.y == 2) {
        if (blockIdx.x >= 1024) return;
        float* h1s = (float*)hbuf;  // reuse LDS: [4][128] fp32
        const int b = blockIdx.x * 4 + w;
        const float* xb = x + (size_t)b * 514;
        const float f0 = xb[0], f1 = xb[1], f2 = t[b];
        float h0, h1;
        {
            const int u0 = lane, u1 = lane + 64;
            h0 = fmaxf(iW1[u0] + 0.f, -1e30f); // placeholder overwritten below
            h0 = fmaxf(iW1[u0] * f0 + iW1[128 + u0] * f1 + iW1[256 + u0] * f2 + ib1[u0], 0.f);
            h1 = fmaxf(iW1[u1] * f0 + iW1[128 + u1] * f1 + iW1[256 + u1] * f2 + ib1[u1], 0.f);
            h1s[w * 128 + u0] = h0;
            h1s[w * 128 + u1] = h1;
        }
        __syncthreads();
        float a0 = ib2[lane], a1 = ib2[lane + 64];
        for (int k = 0; k < 128; ++k) {
            const float hv = h1s[w * 128 + k];
            a0 += hv * iW2[k * 128 + lane];
            a1 += hv * iW2[k * 128 + lane + 64];
        }
        a0 = fmaxf(a0, 0.f); a1 = fmaxf(a1, 0.f);
        float p0 = a0 * iW3[lane * 2 + 0] + a1 * iW3[(lane + 64) * 2 + 0];
        float p1 = a0 * iW3[lane * 2 + 1] + a1 * iW3[(lane + 64) * 2 + 1];
        for (int m = 1; m < 64; m <<= 1) {
            p0 += __shfl_xor(p0, m, 64);
            p1 += __shfl_xor(p1, m, 64);
        }
        if (lane == 0) {
            atomicAdd(&out[(size_t)b * 512 + 0], p0 + ib3[0]);
            atomicAdd(&out[(size_t)b * 512 + 1], p1 + ib3[1]);
        }
        return;
    }

    // ---------------- fwd / bwd MLP path ----------------
    const int dir = blockIdx.y;  // 0 fwd, 1 bwd
    const float* W1 = dir ? gW1 : fW1;
    const float* B1 = dir ? gb1 : fb1;
    const float* W2 = dir ? gW2 : fW2;
    const float* B2 = dir ? gb2 : fb2;
    const float* W3 = dir ? gW3 : fW3;
    const float* B3 = dir ? gb3 : fb3;

    const int wbase = w * 32;

    // Per-lane weight fragments, loaded once (scattered but L2-hot).
    // B-frag layout: element j <-> B[k = ks*32 + q*8 + j][n = lane&15].
    short8 w1f[2], w2f[2][4], w3f[4];
    float  b1v[2], b2v[2];
    #pragma unroll
    for (int ntl = 0; ntl < 2; ++ntl) {
        const int col = wbase + ntl * 16 + c;
        b1v[ntl] = B1[col];
        b2v[ntl] = B2[col];
        short8 f = {0, 0, 0, 0, 0, 0, 0, 0};
        if (q == 0) {  // K padded 8 -> 32: only quad 0 holds real W1 rows
            #pragma unroll
            for (int j = 0; j < 8; ++j) f[j] = (short)f2bf(W1[j * 128 + col]);
        }
        w1f[ntl] = f;
        #pragma unroll
        for (int ks = 0; ks < 4; ++ks) {
            short8 g;
            #pragma unroll
            for (int j = 0; j < 8; ++j)
                g[j] = (short)f2bf(W2[(ks * 32 + q * 8 + j) * 128 + col]);
            w2f[ntl][ks] = g;
        }
    }
    const float b3c = (c < 2) ? B3[c] : 0.0f;
    #pragma unroll
    for (int ks = 0; ks < 4; ++ks) {  // W3: N padded 2 -> 16
        short8 f = {0, 0, 0, 0, 0, 0, 0, 0};
        if (c < 2) {
            #pragma unroll
            for (int j = 0; j < 8; ++j)
                f[j] = (short)f2bf(W3[(ks * 32 + q * 8 + j) * 2 + c]);
        }
        w3f[ks] = f;
    }

    for (int it = 0; it < 4; ++it) {
        const int tt = blockIdx.x + it * 2040;   // 8160 tiles per direction
        const int r0 = tt * 128;

        // ---- stage features: row r -> (b = r/255, i = r%255) ----
        if (tid < 128) {
            const int r = r0 + tid;
            const int b = r / 255;
            const int i = r - b * 255;
            const float* xb = x + (size_t)b * 514;
            const float2 xi  = *(const float2*)(xb + 2 * i);
            const float2 xi1 = *(const float2*)(xb + 2 * i + 2);
            const float2 pt  = *(const float2*)(xb + 512);   // x[b, T, :]
            const float tv = t[b];
            const float nv = (float)(dir ? i : (i + 1)) * (1.0f / 256.0f);
            short8 v;
            if (dir == 0) {  // [x_{i+1}, t, x_i, (i+1)/T, pt]
                v[0] = (short)f2bf(xi1.x); v[1] = (short)f2bf(xi1.y);
                v[2] = (short)f2bf(tv);
                v[3] = (short)f2bf(xi.x);  v[4] = (short)f2bf(xi.y);
            } else {         // [x_i, t, x_{i+1}, i/T, pt]
                v[0] = (short)f2bf(xi.x);  v[1] = (short)f2bf(xi.y);
                v[2] = (short)f2bf(tv);
                v[3] = (short)f2bf(xi1.x); v[4] = (short)f2bf(xi1.y);
            }
            v[5] = (short)f2bf(nv);
            v[6] = (short)f2bf(pt.x); v[7] = (short)f2bf(pt.y);
            *(short8*)&fbuf[tid * 8] = v;
        }
        __syncthreads();  // feats ready; prev-iter hbuf reads drained

        // ---- layer 1: h1[cols wbase..wbase+32) for all 128 rows ----
        #pragma unroll
        for (int mt = 0; mt < 8; ++mt) {
            short8 af = {0, 0, 0, 0, 0, 0, 0, 0};
            if (q == 0) af = *(const short8*)&fbuf[(mt * 16 + c) * 8];
            floatx4 a0 = {b1v[0], b1v[0], b1v[0], b1v[0]};
            floatx4 a1 = {b1v[1], b1v[1], b1v[1], b1v[1]};
            a0 = MFMA16(af, w1f[0], a0);
            a1 = MFMA16(af, w1f[1], a1);
            const int rowb = mt * 16 + q * 4;
            #pragma unroll
            for (int rr = 0; rr < 4; ++rr) {
                hbuf[hidx(rowb + rr, wbase + c)]      = f2bf(fmaxf(a0[rr], 0.0f));
                hbuf[hidx(rowb + rr, wbase + 16 + c)] = f2bf(fmaxf(a1[rr], 0.0f));
            }
        }
        __syncthreads();  // h1 complete

        // ---- layer 2: read all of h1, keep packed bf16 results in regs ----
        unsigned pk[8][4];  // relu(h2) packed: [mt][rr] = lo:ntl0 hi:ntl1
        #pragma unroll
        for (int mt = 0; mt < 8; ++mt) {
            const int row = mt * 16 + c;
            const int sw = (row & 15);
            const unsigned short* rp = &hbuf[row * 128];
            short8 a0 = *(const short8*)&rp[((0 + q) ^ sw) << 3];
            short8 a1 = *(const short8*)&rp[((4 + q) ^ sw) << 3];
            short8 a2 = *(const short8*)&rp[((8 + q) ^ sw) << 3];
            short8 a3 = *(const short8*)&rp[((12 + q) ^ sw) << 3];
            floatx4 s0 = {b2v[0], b2v[0], b2v[0], b2v[0]};
            floatx4 s1 = {b2v[1], b2v[1], b2v[1], b2v[1]};
            s0 = MFMA16(a0, w2f[0][0], s0); s1 = MFMA16(a0, w2f[1][0], s1);
            s0 = MFMA16(a1, w2f[0][1], s0); s1 = MFMA16(a1, w2f[1][1], s1);
            s0 = MFMA16(a2, w2f[0][2], s0); s1 = MFMA16(a2, w2f[1][2], s1);
            s0 = MFMA16(a3, w2f[0][3], s0); s1 = MFMA16(a3, w2f[1][3], s1);
            #pragma unroll
            for (int rr = 0; rr < 4; ++rr)
                pk[mt][rr] = (unsigned)f2bf(fmaxf(s0[rr], 0.0f)) |
                             ((unsigned)f2bf(fmaxf(s1[rr], 0.0f)) << 16);
        }
        __syncthreads();  // all h1 reads done; hbuf reusable for h2
        #pragma unroll
        for (int mt = 0; mt < 8; ++mt) {
            const int rowb = mt * 16 + q * 4;
            #pragma unroll
            for (int rr = 0; rr < 4; ++rr) {
                hbuf[hidx(rowb + rr, wbase + c)]      = (unsigned short)pk[mt][rr];
                hbuf[hidx(rowb + rr, wbase + 16 + c)] = (unsigned short)(pk[mt][rr] >> 16);
            }
        }
        __syncthreads();  // h2 complete

        // ---- layer 3: wave owns rows [32w, 32w+32); atomic-add outputs ----
        #pragma unroll
        for (int mm = 0; mm < 2; ++mm) {
            const int mt = w * 2 + mm;
            const int row = mt * 16 + c;
            const int sw = (row & 15);
            const unsigned short* rp = &hbuf[row * 128];
            short8 a0 = *(const short8*)&rp[((0 + q) ^ sw) << 3];
            short8 a1 = *(const short8*)&rp[((4 + q) ^ sw) << 3];
            short8 a2 = *(const short8*)&rp[((8 + q) ^ sw) << 3];
            short8 a3 = *(const short8*)&rp[((12 + q) ^ sw) << 3];
            floatx4 s = {b3c, b3c, b3c, b3c};
            s = MFMA16(a0, w3f[0], s);
            s = MFMA16(a1, w3f[1], s);
            s = MFMA16(a2, w3f[2], s);
            s = MFMA16(a3, w3f[3], s);
            if (c < 2) {
                const int rowb = mt * 16 + q * 4;
                #pragma unroll
                for (int rr = 0; rr < 4; ++rr) {
                    const int r = r0 + rowb + rr;
                    const int b = r / 255;
                    const int i = r - b * 255;
                    const int pos = i + (dir == 0 ? 1 : 0);
                    atomicAdd(&out[((size_t)b * 256 + pos) * 2 + c], s[rr]);
                }
            }
        }
        // loop-top __syncthreads orders h2 reads vs next-iter h1 writes
    }
}

extern "C" void kernel_launch(void* const* d_in, const int* in_sizes, int n_in,
                              void* d_out, int out_size, void* d_ws, size_t ws_size,
                              hipStream_t stream) {
    (void)in_sizes; (void)n_in; (void)d_ws; (void)ws_size;
    const float* x   = (const float*)d_in[0];
    const float* t   = (const float*)d_in[1];
    const float* fW1 = (const float*)d_in[2];
    const float* fb1 = (const float*)d_in[3];
    const float* fW2 = (const float*)d_in[4];
    const float* fb2 = (const float*)d_in[5];
    const float* fW3 = (const float*)d_in[6];
    const float* fb3 = (const float*)d_in[7];
    const float* gW1 = (const float*)d_in[8];
    const float* gb1 = (const float*)d_in[9];
    const float* gW2 = (const float*)d_in[10];
    const float* gb2 = (const float*)d_in[11];
    const float* gW3 = (const float*)d_in[12];
    const float* gb3 = (const float*)d_in[13];
    const float* iW1 = (const float*)d_in[14];
    const float* ib1 = (const float*)d_in[15];
    const float* iW2 = (const float*)d_in[16];
    const float* ib2 = (const float*)d_in[17];
    const float* iW3 = (const float*)d_in[18];
    const float* ib3 = (const float*)d_in[19];
    float* out = (float*)d_out;

    hipMemsetAsync(d_out, 0, (size_t)out_size * sizeof(float), stream);
    NeuralNet_37615323578557_kernel<<<dim3(2040, 3), 256, 0, stream>>>(
        x, t, fW1, fb1, fW2, fb2, fW3, fb3,
        gW1, gb1, gW2, gb2, gW3, gb3,
        iW1, ib1, iW2, ib2, iW3, ib3, out);
}

// Round 2
// 634.841 us; speedup vs baseline: 1.2142x; 1.2142x over previous
//
#include <hip/hip_runtime.h>
#include <stdint.h>

typedef __attribute__((ext_vector_type(8))) short short8;
typedef __attribute__((ext_vector_type(4))) float floatx4;

#define MFMA16(a, b, c) __builtin_amdgcn_mfma_f32_16x16x32_bf16(a, b, c, 0, 0, 0)

__device__ __forceinline__ unsigned short f2bf(float x) {
    unsigned u = __builtin_bit_cast(unsigned, x);
    u = (u + 0x7fffu + ((u >> 16) & 1u)) >> 16;  // RNE
    return (unsigned short)u;
}

// hbuf is a 128x128 bf16 activation tile viewed as u32 pairs: u32 index u
// holds bf16 cols (2u, 2u+1) of a row. 16B chunks XOR-swizzled by row so
// b32 C-writes are <=2-way and b128 A-frag reads are bank-even.
__device__ __forceinline__ int hphys(int row, int u) {
    return row * 64 + ((((u >> 2) ^ (row & 15)) << 2) | (u & 3));
}

// Grid: 2048 WGs; WG owns batch rows [2*bx, 2*bx+2) completely.
// Sequence: zero accT -> init-MLP -> {fwd, bwd} x 4 tiles of 128 rows
// (510 real rows) -> coalesced writeout. No global atomics.
// N-split: wave w owns hidden cols [32w,32w+32) for layers 1-2 (W1/W2
// B-frags permanently in regs, even/odd col pairing for packed b32 LDS
// writes). Layer 3 is M-split (wave w owns rows [32w,32w+32)).
__global__ __launch_bounds__(256, 4)
void NeuralNet_37615323578557_kernel(
        const float* __restrict__ x, const float* __restrict__ t,
        const float* __restrict__ fW1, const float* __restrict__ fb1,
        const float* __restrict__ fW2, const float* __restrict__ fb2,
        const float* __restrict__ fW3, const float* __restrict__ fb3,
        const float* __restrict__ gW1, const float* __restrict__ gb1,
        const float* __restrict__ gW2, const float* __restrict__ gb2,
        const float* __restrict__ gW3, const float* __restrict__ gb3,
        const float* __restrict__ iW1, const float* __restrict__ ib1,
        const float* __restrict__ iW2, const float* __restrict__ ib2,
        const float* __restrict__ iW3, const float* __restrict__ ib3,
        float* __restrict__ out) {
    __shared__ unsigned hbuf32[128 * 64];       // 32 KB activation tile
    __shared__ unsigned short fbuf[128 * 8];    // 2 KB feature staging
    __shared__ float accT[2 * 256 * 2];         // 4 KB output accumulator

    const int tid  = threadIdx.x;
    const int lane = tid & 63;
    const int w    = tid >> 6;      // wave 0..3
    const int c    = lane & 15;     // MFMA low index (m for A, n for B/C)
    const int q    = lane >> 4;     // MFMA quad
    const int b0   = blockIdx.x * 2;

    // ---- zero the output accumulator ----
    #pragma unroll
    for (int k = 0; k < 4; ++k) accT[tid + k * 256] = 0.0f;
    __syncthreads();

    // ---- init MLP: waves 0,1 handle b_local = w (pure fp32 VALU) ----
    if (w < 2) {
        float* h1s = (float*)hbuf32 + w * 128;  // wave-private scratch
        const int b = b0 + w;
        const float* xb = x + (size_t)b * 514;
        const float f0 = xb[0], f1 = xb[1], f2 = t[b];
        const int u0 = lane, u1 = lane + 64;
        const float h0 = fmaxf(iW1[u0] * f0 + iW1[128 + u0] * f1 + iW1[256 + u0] * f2 + ib1[u0], 0.f);
        const float h1 = fmaxf(iW1[u1] * f0 + iW1[128 + u1] * f1 + iW1[256 + u1] * f2 + ib1[u1], 0.f);
        h1s[u0] = h0;
        h1s[u1] = h1;
        float a0 = ib2[lane], a1 = ib2[lane + 64];
        for (int k = 0; k < 128; ++k) {
            const float hv = h1s[k];
            a0 += hv * iW2[k * 128 + lane];
            a1 += hv * iW2[k * 128 + lane + 64];
        }
        a0 = fmaxf(a0, 0.f); a1 = fmaxf(a1, 0.f);
        float p0 = a0 * iW3[lane * 2 + 0] + a1 * iW3[(lane + 64) * 2 + 0];
        float p1 = a0 * iW3[lane * 2 + 1] + a1 * iW3[(lane + 64) * 2 + 1];
        #pragma unroll
        for (int m = 1; m < 64; m <<= 1) {
            p0 += __shfl_xor(p0, m, 64);
            p1 += __shfl_xor(p1, m, 64);
        }
        if (lane == 0) {
            accT[w * 512 + 0] += p0 + ib3[0];
            accT[w * 512 + 1] += p1 + ib3[1];
        }
    }

    const int wbase = w * 32;
    const int ucol  = w * 16 + c;   // u32 col index this lane writes

    for (int dir = 0; dir < 2; ++dir) {
        const float* W1 = dir ? gW1 : fW1;
        const float* B1 = dir ? gb1 : fb1;
        const float* W2 = dir ? gW2 : fW2;
        const float* B2 = dir ? gb2 : fb2;
        const float* W3 = dir ? gW3 : fW3;
        const float* B3 = dir ? gb3 : fb3;

        // ---- weight fragments (even/odd column pairing) ----
        // frag ntl: n-index c <-> column wbase + 2c + ntl
        short8 w1f[2], w2f[2][4], w3f[4];
        float  b1v[2], b2v[2];
        #pragma unroll
        for (int ntl = 0; ntl < 2; ++ntl) {
            const int col = wbase + 2 * c + ntl;
            b1v[ntl] = B1[col];
            b2v[ntl] = B2[col];
            short8 f = {0, 0, 0, 0, 0, 0, 0, 0};
            if (q == 0) {  // K padded 8 -> 32: only quad 0 holds real W1 rows
                #pragma unroll
                for (int j = 0; j < 8; ++j) f[j] = (short)f2bf(W1[j * 128 + col]);
            }
            w1f[ntl] = f;
            #pragma unroll
            for (int ks = 0; ks < 4; ++ks) {
                short8 g;
                #pragma unroll
                for (int j = 0; j < 8; ++j)
                    g[j] = (short)f2bf(W2[(ks * 32 + q * 8 + j) * 128 + col]);
                w2f[ntl][ks] = g;
            }
        }
        const float b3c = (c < 2) ? B3[c] : 0.0f;
        #pragma unroll
        for (int ks = 0; ks < 4; ++ks) {  // W3: N padded 2 -> 16
            short8 f = {0, 0, 0, 0, 0, 0, 0, 0};
            if (c < 2) {
                #pragma unroll
                for (int j = 0; j < 8; ++j)
                    f[j] = (short)f2bf(W3[(ks * 32 + q * 8 + j) * 2 + c]);
            }
            w3f[ks] = f;
        }

        for (int tt = 0; tt < 4; ++tt) {
            const int r0 = tt * 128;
            __syncthreads();  // hbuf/fbuf free (prev tile reads + init done)

            // ---- stage features: local row r -> (b_local=r/255, i=r%255) ----
            if (tid < 128) {
                const int r = r0 + tid;
                short8 v = {0, 0, 0, 0, 0, 0, 0, 0};
                if (r < 510) {
                    const int bl = r / 255;
                    const int i  = r - bl * 255;
                    const float* xb = x + (size_t)(b0 + bl) * 514;
                    const float2 xi  = *(const float2*)(xb + 2 * i);
                    const float2 xi1 = *(const float2*)(xb + 2 * i + 2);
                    const float2 pt  = *(const float2*)(xb + 512);   // x[b, T, :]
                    const float tv = t[b0 + bl];
                    const float nv = (float)(dir ? i : (i + 1)) * (1.0f / 256.0f);
                    if (dir == 0) {  // [x_{i+1}, t, x_i, (i+1)/T, pt]
                        v[0] = (short)f2bf(xi1.x); v[1] = (short)f2bf(xi1.y);
                        v[2] = (short)f2bf(tv);
                        v[3] = (short)f2bf(xi.x);  v[4] = (short)f2bf(xi.y);
                    } else {         // [x_i, t, x_{i+1}, i/T, pt]
                        v[0] = (short)f2bf(xi.x);  v[1] = (short)f2bf(xi.y);
                        v[2] = (short)f2bf(tv);
                        v[3] = (short)f2bf(xi1.x); v[4] = (short)f2bf(xi1.y);
                    }
                    v[5] = (short)f2bf(nv);
                    v[6] = (short)f2bf(pt.x); v[7] = (short)f2bf(pt.y);
                }
                *(short8*)&fbuf[tid * 8] = v;
            }
            __syncthreads();  // feats ready

            // ---- layer 1: h1[cols wbase..wbase+32) for all 128 rows ----
            #pragma unroll
            for (int mt = 0; mt < 8; ++mt) {
                short8 af = {0, 0, 0, 0, 0, 0, 0, 0};
                if (q == 0) af = *(const short8*)&fbuf[(mt * 16 + c) * 8];
                floatx4 a0 = {b1v[0], b1v[0], b1v[0], b1v[0]};
                floatx4 a1 = {b1v[1], b1v[1], b1v[1], b1v[1]};
                a0 = MFMA16(af, w1f[0], a0);
                a1 = MFMA16(af, w1f[1], a1);
                const int rowb = mt * 16 + q * 4;
                #pragma unroll
                for (int rr = 0; rr < 4; ++rr) {
                    const unsigned pv = (unsigned)f2bf(fmaxf(a0[rr], 0.0f)) |
                                        ((unsigned)f2bf(fmaxf(a1[rr], 0.0f)) << 16);
                    hbuf32[hphys(rowb + rr, ucol)] = pv;
                }
            }
            __syncthreads();  // h1 complete

            // ---- layer 2: read all of h1, keep packed bf16 h2 in regs ----
            unsigned pk[8][4];
            #pragma unroll
            for (int mt = 0; mt < 8; ++mt) {
                const int row = mt * 16 + c;
                const int sw  = row & 15;
                const unsigned* rp = &hbuf32[row * 64];
                short8 a0 = *(const short8*)&rp[((0 ^ sw) << 2)];
                short8 a1 = *(const short8*)&rp[(((4 + q) ^ sw) << 2)];
                short8 a2 = *(const short8*)&rp[(((8 + q) ^ sw) << 2)];
                short8 a3 = *(const short8*)&rp[(((12 + q) ^ sw) << 2)];
                short8 aa = *(const short8*)&rp[(((0 + q) ^ sw) << 2)];
                floatx4 s0 = {b2v[0], b2v[0], b2v[0], b2v[0]};
                floatx4 s1 = {b2v[1], b2v[1], b2v[1], b2v[1]};
                s0 = MFMA16(aa, w2f[0][0], s0); s1 = MFMA16(aa, w2f[1][0], s1);
                s0 = MFMA16(a1, w2f[0][1], s0); s1 = MFMA16(a1, w2f[1][1], s1);
                s0 = MFMA16(a2, w2f[0][2], s0); s1 = MFMA16(a2, w2f[1][2], s1);
                s0 = MFMA16(a3, w2f[0][3], s0); s1 = MFMA16(a3, w2f[1][3], s1);
                #pragma unroll
                for (int rr = 0; rr < 4; ++rr)
                    pk[mt][rr] = (unsigned)f2bf(fmaxf(s0[rr], 0.0f)) |
                                 ((unsigned)f2bf(fmaxf(s1[rr], 0.0f)) << 16);
            }
            __syncthreads();  // all h1 reads done; hbuf reusable for h2
            #pragma unroll
            for (int mt = 0; mt < 8; ++mt) {
                const int rowb = mt * 16 + q * 4;
                #pragma unroll
                for (int rr = 0; rr < 4; ++rr)
                    hbuf32[hphys(rowb + rr, ucol)] = pk[mt][rr];
            }
            __syncthreads();  // h2 complete

            // ---- layer 3: wave owns rows [32w,32w+32); add into accT ----
            #pragma unroll
            for (int mm = 0; mm < 2; ++mm) {
                const int row = w * 32 + mm * 16 + c;
                const int sw  = row & 15;
                const unsigned* rp = &hbuf32[row * 64];
                short8 a0 = *(const short8*)&rp[(((0 + q) ^ sw) << 2)];
                short8 a1 = *(const short8*)&rp[(((4 + q) ^ sw) << 2)];
                short8 a2 = *(const short8*)&rp[(((8 + q) ^ sw) << 2)];
                short8 a3 = *(const short8*)&rp[(((12 + q) ^ sw) << 2)];
                floatx4 s = {b3c, b3c, b3c, b3c};
                s = MFMA16(a0, w3f[0], s);
                s = MFMA16(a1, w3f[1], s);
                s = MFMA16(a2, w3f[2], s);
                s = MFMA16(a3, w3f[3], s);
                if (c < 2) {
                    const int rowb = w * 32 + mm * 16 + q * 4;
                    #pragma unroll
                    for (int rr = 0; rr < 4; ++rr) {
                        const int r = r0 + rowb + rr;
                        if (r < 510) {
                            const int bl = r / 255;
                            const int i  = r - bl * 255;
                            const int pos = i + 1 - dir;
                            accT[(bl << 9) + pos * 2 + c] += s[rr];
                        }
                    }
                }
            }
            // loop-top barrier orders h2 reads vs next-tile writes
        }
    }

    __syncthreads();  // accT complete
    // ---- coalesced writeout: 1024 floats = out[b0..b0+1] ----
    ((float4*)(out + (size_t)b0 * 512))[tid] = ((const float4*)accT)[tid];
}

extern "C" void kernel_launch(void* const* d_in, const int* in_sizes, int n_in,
                              void* d_out, int out_size, void* d_ws, size_t ws_size,
                              hipStream_t stream) {
    (void)in_sizes; (void)n_in; (void)d_ws; (void)ws_size; (void)out_size;
    const float* x   = (const float*)d_in[0];
    const float* t   = (const float*)d_in[1];
    const float* fW1 = (const float*)d_in[2];
    const float* fb1 = (const float*)d_in[3];
    const float* fW2 = (const float*)d_in[4];
    const float* fb2 = (const float*)d_in[5];
    const float* fW3 = (const float*)d_in[6];
    const float* fb3 = (const float*)d_in[7];
    const float* gW1 = (const float*)d_in[8];
    const float* gb1 = (const float*)d_in[9];
    const float* gW2 = (const float*)d_in[10];
    const float* gb2 = (const float*)d_in[11];
    const float* gW3 = (const float*)d_in[12];
    const float* gb3 = (const float*)d_in[13];
    const float* iW1 = (const float*)d_in[14];
    const float* ib1 = (const float*)d_in[15];
    const float* iW2 = (const float*)d_in[16];
    const float* ib2 = (const float*)d_in[17];
    const float* iW3 = (const float*)d_in[18];
    const float* ib3 = (const float*)d_in[19];
    float* out = (float*)d_out;

    NeuralNet_37615323578557_kernel<<<dim3(2048), 256, 0, stream>>>(
        x, t, fW1, fb1, fW2, fb2, fW3, fb3,
        gW1, gb1, gW2, gb2, gW3, gb3,
        iW1, ib1, iW2, ib2, iW3, ib3, out);
}

// Round 3
// 358.186 us; speedup vs baseline: 2.1520x; 1.7724x over previous
//
#include <hip/hip_runtime.h>
#include <stdint.h>

typedef __attribute__((ext_vector_type(8))) short short8;
typedef __attribute__((ext_vector_type(4))) float floatx4;

#define MFMA16(a, b, c) __builtin_amdgcn_mfma_f32_16x16x32_bf16(a, b, c, 0, 0, 0)

__device__ __forceinline__ unsigned short f2bf(float x) {
    unsigned u = __builtin_bit_cast(unsigned, x);
    u = (u + 0x7fffu + ((u >> 16) & 1u)) >> 16;  // RNE
    return (unsigned short)u;
}

// Activation tiles are 128x128 bf16 viewed as u32 pairs: u32 index u of a row
// holds bf16 cols (2u, 2u+1). 16B chunks XOR-swizzled by row&15: b32 C-layout
// writes land 2-way (free), b128 A-frag reads are bank-balanced.
__device__ __forceinline__ int hphys(int row, int u) {
    return row * 64 + ((((u >> 2) ^ (row & 15)) << 2) | (u & 3));
}

// Grid: 2048 WGs; WG owns batch rows [2*bx, 2*bx+2) completely — fwd, bwd
// and init contributions all accumulate in LDS (accT), one coalesced
// writeout, no global atomics.
// N-split: wave w owns hidden cols [32w,32w+32) for layers 1-2 (W1/W2
// B-frags permanently in regs; even/odd col pairing -> packed b32 LDS
// writes). Layer 3 is M-split (wave w owns rows [32w,32w+32)).
// h1 and h2 get separate LDS buffers (70 KB total -> 2 WGs/CU) so no
// register array needs to live across a barrier; waves_per_eu(2,2) pins the
// allocator at the 256-VGPR budget so nothing spills to scratch.
__global__ __launch_bounds__(256)
__attribute__((amdgpu_waves_per_eu(2, 2)))
void NeuralNet_37615323578557_kernel(
        const float* __restrict__ x, const float* __restrict__ t,
        const float* __restrict__ fW1, const float* __restrict__ fb1,
        const float* __restrict__ fW2, const float* __restrict__ fb2,
        const float* __restrict__ fW3, const float* __restrict__ fb3,
        const float* __restrict__ gW1, const float* __restrict__ gb1,
        const float* __restrict__ gW2, const float* __restrict__ gb2,
        const float* __restrict__ gW3, const float* __restrict__ gb3,
        const float* __restrict__ iW1, const float* __restrict__ ib1,
        const float* __restrict__ iW2, const float* __restrict__ ib2,
        const float* __restrict__ iW3, const float* __restrict__ ib3,
        float* __restrict__ out) {
    __shared__ unsigned h1buf[128 * 64];        // 32 KB
    __shared__ unsigned h2buf[128 * 64];        // 32 KB
    __shared__ unsigned short fbuf[128 * 8];    // 2 KB feature staging
    __shared__ float accT[2 * 256 * 2];         // 4 KB output accumulator

    const int tid  = threadIdx.x;
    const int lane = tid & 63;
    const int w    = tid >> 6;      // wave 0..3
    const int c    = lane & 15;     // MFMA low index (m for A, n for B/C)
    const int q    = lane >> 4;     // MFMA quad
    const int b0   = blockIdx.x * 2;

    // ---- zero the output accumulator ----
    #pragma unroll
    for (int k = 0; k < 4; ++k) accT[tid + k * 256] = 0.0f;
    __syncthreads();

    // ---- init MLP: waves 0,1 handle b_local = w (pure fp32 VALU) ----
    if (w < 2) {
        float* h1s = (float*)h2buf + w * 128;   // scratch, free until tile0 L2
        const int b = b0 + w;
        const float* xb = x + (size_t)b * 514;
        const float f0 = xb[0], f1 = xb[1], f2 = t[b];
        const int u0 = lane, u1 = lane + 64;
        const float h0 = fmaxf(iW1[u0] * f0 + iW1[128 + u0] * f1 + iW1[256 + u0] * f2 + ib1[u0], 0.f);
        const float h1 = fmaxf(iW1[u1] * f0 + iW1[128 + u1] * f1 + iW1[256 + u1] * f2 + ib1[u1], 0.f);
        h1s[u0] = h0;
        h1s[u1] = h1;
        float a0 = ib2[lane], a1 = ib2[lane + 64];
        for (int k = 0; k < 128; ++k) {
            const float hv = h1s[k];
            a0 += hv * iW2[k * 128 + lane];
            a1 += hv * iW2[k * 128 + lane + 64];
        }
        a0 = fmaxf(a0, 0.f); a1 = fmaxf(a1, 0.f);
        float p0 = a0 * iW3[lane * 2 + 0] + a1 * iW3[(lane + 64) * 2 + 0];
        float p1 = a0 * iW3[lane * 2 + 1] + a1 * iW3[(lane + 64) * 2 + 1];
        #pragma unroll
        for (int m = 1; m < 64; m <<= 1) {
            p0 += __shfl_xor(p0, m, 64);
            p1 += __shfl_xor(p1, m, 64);
        }
        if (lane == 0) {
            accT[w * 512 + 0] += p0 + ib3[0];
            accT[w * 512 + 1] += p1 + ib3[1];
        }
    }

    const int wbase = w * 32;
    const int ucol  = w * 16 + c;   // u32 col index this lane writes

    for (int dir = 0; dir < 2; ++dir) {
        const float* W1 = dir ? gW1 : fW1;
        const float* B1 = dir ? gb1 : fb1;
        const float* W2 = dir ? gW2 : fW2;
        const float* B2 = dir ? gb2 : fb2;
        const float* W3 = dir ? gW3 : fW3;
        const float* B3 = dir ? gb3 : fb3;

        // ---- weight fragments (even/odd column pairing) ----
        // frag ntl: n-index c <-> column wbase + 2c + ntl
        short8 w1f[2], w2f[2][4], w3f[4];
        float  b1v[2], b2v[2];
        #pragma unroll
        for (int ntl = 0; ntl < 2; ++ntl) {
            const int col = wbase + 2 * c + ntl;
            b1v[ntl] = B1[col];
            b2v[ntl] = B2[col];
            short8 f = {0, 0, 0, 0, 0, 0, 0, 0};
            if (q == 0) {  // K padded 8 -> 32: only quad 0 holds real W1 rows
                #pragma unroll
                for (int j = 0; j < 8; ++j) f[j] = (short)f2bf(W1[j * 128 + col]);
            }
            w1f[ntl] = f;
            #pragma unroll
            for (int ks = 0; ks < 4; ++ks) {
                short8 g;
                #pragma unroll
                for (int j = 0; j < 8; ++j)
                    g[j] = (short)f2bf(W2[(ks * 32 + q * 8 + j) * 128 + col]);
                w2f[ntl][ks] = g;
            }
        }
        const float b3c = (c < 2) ? B3[c] : 0.0f;
        #pragma unroll
        for (int ks = 0; ks < 4; ++ks) {  // W3: N padded 2 -> 16
            short8 f = {0, 0, 0, 0, 0, 0, 0, 0};
            if (c < 2) {
                #pragma unroll
                for (int j = 0; j < 8; ++j)
                    f[j] = (short)f2bf(W3[(ks * 32 + q * 8 + j) * 2 + c]);
            }
            w3f[ks] = f;
        }

        for (int tt = 0; tt < 4; ++tt) {
            const int r0 = tt * 128;

            // ---- stage features: local row r -> (b_local=r/255, i=r%255) ----
            // Safe without a leading barrier: last fbuf reads preceded the
            // previous tile's h1-complete barrier.
            if (tid < 128) {
                const int r = r0 + tid;
                short8 v = {0, 0, 0, 0, 0, 0, 0, 0};
                if (r < 510) {
                    const int bl = r / 255;
                    const int i  = r - bl * 255;
                    const float* xb = x + (size_t)(b0 + bl) * 514;
                    const float2 xi  = *(const float2*)(xb + 2 * i);
                    const float2 xi1 = *(const float2*)(xb + 2 * i + 2);
                    const float2 pt  = *(const float2*)(xb + 512);   // x[b, T, :]
                    const float tv = t[b0 + bl];
                    const float nv = (float)(dir ? i : (i + 1)) * (1.0f / 256.0f);
                    if (dir == 0) {  // [x_{i+1}, t, x_i, (i+1)/T, pt]
                        v[0] = (short)f2bf(xi1.x); v[1] = (short)f2bf(xi1.y);
                        v[2] = (short)f2bf(tv);
                        v[3] = (short)f2bf(xi.x);  v[4] = (short)f2bf(xi.y);
                    } else {         // [x_i, t, x_{i+1}, i/T, pt]
                        v[0] = (short)f2bf(xi.x);  v[1] = (short)f2bf(xi.y);
                        v[2] = (short)f2bf(tv);
                        v[3] = (short)f2bf(xi1.x); v[4] = (short)f2bf(xi1.y);
                    }
                    v[5] = (short)f2bf(nv);
                    v[6] = (short)f2bf(pt.x); v[7] = (short)f2bf(pt.y);
                }
                *(short8*)&fbuf[tid * 8] = v;
            }
            __syncthreads();  // feats ready; also orders prev L2-reads vs h1 writes

            // ---- layer 1: h1[cols wbase..wbase+32) for all 128 rows ----
            #pragma unroll
            for (int mt = 0; mt < 8; ++mt) {
                short8 af = {0, 0, 0, 0, 0, 0, 0, 0};
                if (q == 0) af = *(const short8*)&fbuf[(mt * 16 + c) * 8];
                floatx4 a0 = {b1v[0], b1v[0], b1v[0], b1v[0]};
                floatx4 a1 = {b1v[1], b1v[1], b1v[1], b1v[1]};
                a0 = MFMA16(af, w1f[0], a0);
                a1 = MFMA16(af, w1f[1], a1);
                const int rowb = mt * 16 + q * 4;
                #pragma unroll
                for (int rr = 0; rr < 4; ++rr) {
                    const unsigned pv = (unsigned)f2bf(fmaxf(a0[rr], 0.0f)) |
                                        ((unsigned)f2bf(fmaxf(a1[rr], 0.0f)) << 16);
                    h1buf[hphys(rowb + rr, ucol)] = pv;
                }
            }
            __syncthreads();  // h1 complete (also: prev L3 h2-reads all drained)

            // ---- layer 2: read h1, write h2 directly (disjoint buffers) ----
            #pragma unroll
            for (int mt = 0; mt < 8; ++mt) {
                const int row = mt * 16 + c;
                const int sw  = row & 15;
                const unsigned* rp = &h1buf[row * 64];
                short8 a0 = *(const short8*)&rp[(((0 + q) ^ sw) << 2)];
                short8 a1 = *(const short8*)&rp[(((4 + q) ^ sw) << 2)];
                short8 a2 = *(const short8*)&rp[(((8 + q) ^ sw) << 2)];
                short8 a3 = *(const short8*)&rp[(((12 + q) ^ sw) << 2)];
                floatx4 s0 = {b2v[0], b2v[0], b2v[0], b2v[0]};
                floatx4 s1 = {b2v[1], b2v[1], b2v[1], b2v[1]};
                s0 = MFMA16(a0, w2f[0][0], s0); s1 = MFMA16(a0, w2f[1][0], s1);
                s0 = MFMA16(a1, w2f[0][1], s0); s1 = MFMA16(a1, w2f[1][1], s1);
                s0 = MFMA16(a2, w2f[0][2], s0); s1 = MFMA16(a2, w2f[1][2], s1);
                s0 = MFMA16(a3, w2f[0][3], s0); s1 = MFMA16(a3, w2f[1][3], s1);
                const int rowb = mt * 16 + q * 4;
                #pragma unroll
                for (int rr = 0; rr < 4; ++rr) {
                    const unsigned pv = (unsigned)f2bf(fmaxf(s0[rr], 0.0f)) |
                                        ((unsigned)f2bf(fmaxf(s1[rr], 0.0f)) << 16);
                    h2buf[hphys(rowb + rr, ucol)] = pv;
                }
            }
            __syncthreads();  // h2 complete

            // ---- layer 3: wave owns rows [32w,32w+32); add into accT ----
            #pragma unroll
            for (int mm = 0; mm < 2; ++mm) {
                const int row = w * 32 + mm * 16 + c;
                const int sw  = row & 15;
                const unsigned* rp = &h2buf[row * 64];
                short8 a0 = *(const short8*)&rp[(((0 + q) ^ sw) << 2)];
                short8 a1 = *(const short8*)&rp[(((4 + q) ^ sw) << 2)];
                short8 a2 = *(const short8*)&rp[(((8 + q) ^ sw) << 2)];
                short8 a3 = *(const short8*)&rp[(((12 + q) ^ sw) << 2)];
                floatx4 s = {b3c, b3c, b3c, b3c};
                s = MFMA16(a0, w3f[0], s);
                s = MFMA16(a1, w3f[1], s);
                s = MFMA16(a2, w3f[2], s);
                s = MFMA16(a3, w3f[3], s);
                if (c < 2) {
                    const int rowb = w * 32 + mm * 16 + q * 4;
                    #pragma unroll
                    for (int rr = 0; rr < 4; ++rr) {
                        const int r = r0 + rowb + rr;
                        if (r < 510) {
                            const int bl = r / 255;
                            const int i  = r - bl * 255;
                            const int pos = i + 1 - dir;
                            accT[(bl << 9) + pos * 2 + c] += s[rr];
                        }
                    }
                }
            }
            // next tile's h1/h2 writes are ordered by its own barriers
        }
    }

    __syncthreads();  // accT complete
    // ---- coalesced writeout: 1024 floats = out[b0..b0+1] ----
    ((float4*)(out + (size_t)b0 * 512))[tid] = ((const float4*)accT)[tid];
}

extern "C" void kernel_launch(void* const* d_in, const int* in_sizes, int n_in,
                              void* d_out, int out_size, void* d_ws, size_t ws_size,
                              hipStream_t stream) {
    (void)in_sizes; (void)n_in; (void)d_ws; (void)ws_size; (void)out_size;
    const float* x   = (const float*)d_in[0];
    const float* t   = (const float*)d_in[1];
    const float* fW1 = (const float*)d_in[2];
    const float* fb1 = (const float*)d_in[3];
    const float* fW2 = (const float*)d_in[4];
    const float* fb2 = (const float*)d_in[5];
    const float* fW3 = (const float*)d_in[6];
    const float* fb3 = (const float*)d_in[7];
    const float* gW1 = (const float*)d_in[8];
    const float* gb1 = (const float*)d_in[9];
    const float* gW2 = (const float*)d_in[10];
    const float* gb2 = (const float*)d_in[11];
    const float* gW3 = (const float*)d_in[12];
    const float* gb3 = (const float*)d_in[13];
    const float* iW1 = (const float*)d_in[14];
    const float* ib1 = (const float*)d_in[15];
    const float* iW2 = (const float*)d_in[16];
    const float* ib2 = (const float*)d_in[17];
    const float* iW3 = (const float*)d_in[18];
    const float* ib3 = (const float*)d_in[19];
    float* out = (float*)d_out;

    NeuralNet_37615323578557_kernel<<<dim3(2048), 256, 0, stream>>>(
        x, t, fW1, fb1, fW2, fb2, fW3, fb3,
        gW1, gb1, gW2, gb2, gW3, gb3,
        iW1, ib1, iW2, ib2, iW3, ib3, out);
}

// Round 4
// 295.621 us; speedup vs baseline: 2.6075x; 1.2116x over previous
//
#include <hip/hip_runtime.h>
#include <stdint.h>

typedef __attribute__((ext_vector_type(8))) short short8;
typedef __attribute__((ext_vector_type(4))) float floatx4;

#define MFMA16(a, b, c) __builtin_amdgcn_mfma_f32_16x16x32_bf16(a, b, c, 0, 0, 0)

__device__ __forceinline__ unsigned short f2bf(float x) {
    unsigned u = __builtin_bit_cast(unsigned, x);
    u = (u + 0x7fffu + ((u >> 16) & 1u)) >> 16;  // RNE
    return (unsigned short)u;
}

// Activation tiles are 128x128 bf16 viewed as u32 pairs: u32 index u of a row
// holds bf16 cols (2u, 2u+1). 16B chunks XOR-swizzled by row&15: b32 C-layout
// writes land 2-way (free), b128 A-frag reads are bank-balanced.
__device__ __forceinline__ int hphys(int row, int u) {
    return row * 64 + ((((u >> 2) ^ (row & 15)) << 2) | (u & 3));
}

// Grid: 2048 WGs; WG owns batch rows [2*bx, 2*bx+2) completely — fwd, bwd
// and init contributions accumulate in LDS (accT), one coalesced writeout,
// no global atomics.
// N-split: wave w owns hidden cols [32w,32w+32) for layers 1-2; even/odd col
// pairing -> packed b32 LDS writes. Layer 3 is M-split.
// W2 fragments are staged per-dir through LDS (coalesced float4 load ->
// packed bf16 B-frag image in h2buf -> 8 conflict-free ds_read_b128 per
// lane). This kills the scattered-scalar-load register-pressure spike that
// made the compiler scratch-spill w2f in rounds 2-3 (124 MiB of WRITE_SIZE).
__global__ __launch_bounds__(256)
__attribute__((amdgpu_waves_per_eu(2, 2)))
void NeuralNet_37615323578557_kernel(
        const float* __restrict__ x, const float* __restrict__ t,
        const float* __restrict__ fW1, const float* __restrict__ fb1,
        const float* __restrict__ fW2, const float* __restrict__ fb2,
        const float* __restrict__ fW3, const float* __restrict__ fb3,
        const float* __restrict__ gW1, const float* __restrict__ gb1,
        const float* __restrict__ gW2, const float* __restrict__ gb2,
        const float* __restrict__ gW3, const float* __restrict__ gb3,
        const float* __restrict__ iW1, const float* __restrict__ ib1,
        const float* __restrict__ iW2, const float* __restrict__ ib2,
        const float* __restrict__ iW3, const float* __restrict__ ib3,
        float* __restrict__ out) {
    __shared__ unsigned h1buf[128 * 64];        // 32 KB
    __shared__ unsigned h2buf[128 * 64];        // 32 KB (also W2-frag staging)
    __shared__ unsigned short fbuf[128 * 8];    // 2 KB feats / init scratch
    __shared__ float accT[2 * 256 * 2];         // 4 KB output accumulator

    const int tid  = threadIdx.x;
    const int lane = tid & 63;
    const int w    = tid >> 6;      // wave 0..3
    const int c    = lane & 15;     // MFMA low index (m for A, n for B/C)
    const int q    = lane >> 4;     // MFMA quad
    const int b0   = blockIdx.x * 2;

    // ---- zero the output accumulator ----
    #pragma unroll
    for (int k = 0; k < 4; ++k) accT[tid + k * 256] = 0.0f;
    __syncthreads();

    // ---- init MLP: waves 0,1 handle b_local = w (pure fp32 VALU) ----
    // Scratch lives in fbuf (wave-private 512 B each); h2buf stays free for
    // the dir-0 W2 staging that other waves may start concurrently.
    if (w < 2) {
        float* h1s = (float*)fbuf + w * 128;
        const int b = b0 + w;
        const float* xb = x + (size_t)b * 514;
        const float f0 = xb[0], f1 = xb[1], f2 = t[b];
        const int u0 = lane, u1 = lane + 64;
        const float h0 = fmaxf(iW1[u0] * f0 + iW1[128 + u0] * f1 + iW1[256 + u0] * f2 + ib1[u0], 0.f);
        const float h1 = fmaxf(iW1[u1] * f0 + iW1[128 + u1] * f1 + iW1[256 + u1] * f2 + ib1[u1], 0.f);
        h1s[u0] = h0;
        h1s[u1] = h1;
        float a0 = ib2[lane], a1 = ib2[lane + 64];
        for (int k = 0; k < 128; ++k) {
            const float hv = h1s[k];
            a0 += hv * iW2[k * 128 + lane];
            a1 += hv * iW2[k * 128 + lane + 64];
        }
        a0 = fmaxf(a0, 0.f); a1 = fmaxf(a1, 0.f);
        float p0 = a0 * iW3[lane * 2 + 0] + a1 * iW3[(lane + 64) * 2 + 0];
        float p1 = a0 * iW3[lane * 2 + 1] + a1 * iW3[(lane + 64) * 2 + 1];
        #pragma unroll
        for (int m = 1; m < 64; m <<= 1) {
            p0 += __shfl_xor(p0, m, 64);
            p1 += __shfl_xor(p1, m, 64);
        }
        if (lane == 0) {
            accT[w * 512 + 0] += p0 + ib3[0];
            accT[w * 512 + 1] += p1 + ib3[1];
        }
    }

    const int wbase = w * 32;
    const int ucol  = w * 16 + c;   // u32 col index this lane writes

    for (int dir = 0; dir < 2; ++dir) {
        const float* W1 = dir ? gW1 : fW1;
        const float* B1 = dir ? gb1 : fb1;
        const float* W2 = dir ? gW2 : fW2;
        const float* B2 = dir ? gb2 : fb2;
        const float* W3 = dir ? gW3 : fW3;
        const float* B3 = dir ? gb3 : fb3;

        __syncthreads();  // prev dir's h2buf reads (L3) / init fbuf done

        // ---- stage W2 B-frag image into h2buf (exactly 32 KB) ----
        // Element (k,n) -> block B=((n>>5)*2+(n&1))*4+(k>>5),
        //   ushort idx = B*512 + (((k>>3)&3)*16 + ((n>>1)&15))*8 + (k&7).
        // Thread stages rows {k0,k0+1} x cols [c0,c0+32): the k-pair shares
        // ks/q and gives adjacent j -> one packed b32 LDS write per n.
        {
            const int a  = tid >> 2;
            const int k0 = a << 1;
            const int c0 = (tid & 3) << 5;
            const int ks = k0 >> 5;
            const int q2 = (k0 >> 3) & 3;
            const int j0 = k0 & 7;          // even
            const float* r0p = &W2[k0 * 128 + c0];
            const float* r1p = r0p + 128;
            #pragma unroll
            for (int nn = 0; nn < 32; nn += 4) {
                const float4 v0 = *(const float4*)(r0p + nn);
                const float4 v1 = *(const float4*)(r1p + nn);
                #pragma unroll
                for (int e = 0; e < 4; ++e) {
                    const int n = c0 + nn + e;
                    const unsigned pv =
                        (unsigned)f2bf(((const float*)&v0)[e]) |
                        ((unsigned)f2bf(((const float*)&v1)[e]) << 16);
                    const int B = ((n >> 5) * 2 + (n & 1)) * 4 + ks;
                    const int us = B * 512 + (q2 * 16 + ((n >> 1) & 15)) * 8 + j0;
                    h2buf[us >> 1] = pv;
                }
            }
        }

        // ---- small weight frags (W1, W3, biases) straight to regs ----
        short8 w1f[2], w3f[4];
        float  b1v[2], b2v[2];
        #pragma unroll
        for (int ntl = 0; ntl < 2; ++ntl) {
            const int col = wbase + 2 * c + ntl;
            b1v[ntl] = B1[col];
            b2v[ntl] = B2[col];
            short8 f = {0, 0, 0, 0, 0, 0, 0, 0};
            if (q == 0) {  // K padded 8 -> 32: only quad 0 holds real W1 rows
                #pragma unroll
                for (int j = 0; j < 8; ++j) f[j] = (short)f2bf(W1[j * 128 + col]);
            }
            w1f[ntl] = f;
        }
        const float b3c = (c < 2) ? B3[c] : 0.0f;
        #pragma unroll
        for (int ks = 0; ks < 4; ++ks) {  // W3: N padded 2 -> 16
            short8 f = {0, 0, 0, 0, 0, 0, 0, 0};
            if (c < 2) {
                #pragma unroll
                for (int j = 0; j < 8; ++j)
                    f[j] = (short)f2bf(W3[(ks * 32 + q * 8 + j) * 2 + c]);
            }
            w3f[ks] = f;
        }
        __syncthreads();  // W2 frag image complete

        // ---- w2f from LDS: 8 conflict-free ds_read_b128 per lane ----
        short8 w2f[2][4];
        {
            const unsigned short* img = (const unsigned short*)h2buf;
            #pragma unroll
            for (int ntl = 0; ntl < 2; ++ntl)
                #pragma unroll
                for (int ks = 0; ks < 4; ++ks)
                    w2f[ntl][ks] = *(const short8*)
                        &img[(((w * 2 + ntl) * 4 + ks) << 9) + lane * 8];
        }

        for (int tt = 0; tt < 4; ++tt) {
            const int r0 = tt * 128;

            // ---- stage features: local row r -> (b_local=r/255, i=r%255) ----
            // Safe: last fbuf reads preceded the prior barrier.
            if (tid < 128) {
                const int r = r0 + tid;
                short8 v = {0, 0, 0, 0, 0, 0, 0, 0};
                if (r < 510) {
                    const int bl = r / 255;
                    const int i  = r - bl * 255;
                    const float* xb = x + (size_t)(b0 + bl) * 514;
                    const float2 xi  = *(const float2*)(xb + 2 * i);
                    const float2 xi1 = *(const float2*)(xb + 2 * i + 2);
                    const float2 pt  = *(const float2*)(xb + 512);   // x[b, T, :]
                    const float tv = t[b0 + bl];
                    const float nv = (float)(dir ? i : (i + 1)) * (1.0f / 256.0f);
                    if (dir == 0) {  // [x_{i+1}, t, x_i, (i+1)/T, pt]
                        v[0] = (short)f2bf(xi1.x); v[1] = (short)f2bf(xi1.y);
                        v[2] = (short)f2bf(tv);
                        v[3] = (short)f2bf(xi.x);  v[4] = (short)f2bf(xi.y);
                    } else {         // [x_i, t, x_{i+1}, i/T, pt]
                        v[0] = (short)f2bf(xi.x);  v[1] = (short)f2bf(xi.y);
                        v[2] = (short)f2bf(tv);
                        v[3] = (short)f2bf(xi1.x); v[4] = (short)f2bf(xi1.y);
                    }
                    v[5] = (short)f2bf(nv);
                    v[6] = (short)f2bf(pt.x); v[7] = (short)f2bf(pt.y);
                }
                *(short8*)&fbuf[tid * 8] = v;
            }
            __syncthreads();  // feats ready; w2f reads drained (pre-barrier)

            // ---- layer 1: h1[cols wbase..wbase+32) for all 128 rows ----
            #pragma unroll
            for (int mt = 0; mt < 8; ++mt) {
                short8 af = {0, 0, 0, 0, 0, 0, 0, 0};
                if (q == 0) af = *(const short8*)&fbuf[(mt * 16 + c) * 8];
                floatx4 a0 = {b1v[0], b1v[0], b1v[0], b1v[0]};
                floatx4 a1 = {b1v[1], b1v[1], b1v[1], b1v[1]};
                a0 = MFMA16(af, w1f[0], a0);
                a1 = MFMA16(af, w1f[1], a1);
                const int rowb = mt * 16 + q * 4;
                #pragma unroll
                for (int rr = 0; rr < 4; ++rr) {
                    const unsigned pv = (unsigned)f2bf(fmaxf(a0[rr], 0.0f)) |
                                        ((unsigned)f2bf(fmaxf(a1[rr], 0.0f)) << 16);
                    h1buf[hphys(rowb + rr, ucol)] = pv;
                }
            }
            __syncthreads();  // h1 complete (also: prev L3 h2-reads drained)

            // ---- layer 2: read h1, write h2 (disjoint buffers) ----
            #pragma unroll
            for (int mt = 0; mt < 8; ++mt) {
                const int row = mt * 16 + c;
                const int sw  = row & 15;
                const unsigned* rp = &h1buf[row * 64];
                short8 a0 = *(const short8*)&rp[(((0 + q) ^ sw) << 2)];
                short8 a1 = *(const short8*)&rp[(((4 + q) ^ sw) << 2)];
                short8 a2 = *(const short8*)&rp[(((8 + q) ^ sw) << 2)];
                short8 a3 = *(const short8*)&rp[(((12 + q) ^ sw) << 2)];
                floatx4 s0 = {b2v[0], b2v[0], b2v[0], b2v[0]};
                floatx4 s1 = {b2v[1], b2v[1], b2v[1], b2v[1]};
                s0 = MFMA16(a0, w2f[0][0], s0); s1 = MFMA16(a0, w2f[1][0], s1);
                s0 = MFMA16(a1, w2f[0][1], s0); s1 = MFMA16(a1, w2f[1][1], s1);
                s0 = MFMA16(a2, w2f[0][2], s0); s1 = MFMA16(a2, w2f[1][2], s1);
                s0 = MFMA16(a3, w2f[0][3], s0); s1 = MFMA16(a3, w2f[1][3], s1);
                const int rowb = mt * 16 + q * 4;
                #pragma unroll
                for (int rr = 0; rr < 4; ++rr) {
                    const unsigned pv = (unsigned)f2bf(fmaxf(s0[rr], 0.0f)) |
                                        ((unsigned)f2bf(fmaxf(s1[rr], 0.0f)) << 16);
                    h2buf[hphys(rowb + rr, ucol)] = pv;
                }
            }
            __syncthreads();  // h2 complete

            // ---- layer 3: wave owns rows [32w,32w+32); add into accT ----
            #pragma unroll
            for (int mm = 0; mm < 2; ++mm) {
                const int row = w * 32 + mm * 16 + c;
                const int sw  = row & 15;
                const unsigned* rp = &h2buf[row * 64];
                short8 a0 = *(const short8*)&rp[(((0 + q) ^ sw) << 2)];
                short8 a1 = *(const short8*)&rp[(((4 + q) ^ sw) << 2)];
                short8 a2 = *(const short8*)&rp[(((8 + q) ^ sw) << 2)];
                short8 a3 = *(const short8*)&rp[(((12 + q) ^ sw) << 2)];
                floatx4 s = {b3c, b3c, b3c, b3c};
                s = MFMA16(a0, w3f[0], s);
                s = MFMA16(a1, w3f[1], s);
                s = MFMA16(a2, w3f[2], s);
                s = MFMA16(a3, w3f[3], s);
                if (c < 2) {
                    const int rowb = w * 32 + mm * 16 + q * 4;
                    #pragma unroll
                    for (int rr = 0; rr < 4; ++rr) {
                        const int r = r0 + rowb + rr;
                        if (r < 510) {
                            const int bl = r / 255;
                            const int i  = r - bl * 255;
                            const int pos = i + 1 - dir;
                            accT[(bl << 9) + pos * 2 + c] += s[rr];
                        }
                    }
                }
            }
            // next tile's writes ordered by its own barriers
        }
    }

    __syncthreads();  // accT complete
    // ---- coalesced writeout: 1024 floats = out[b0..b0+1] ----
    ((float4*)(out + (size_t)b0 * 512))[tid] = ((const float4*)accT)[tid];
}

extern "C" void kernel_launch(void* const* d_in, const int* in_sizes, int n_in,
                              void* d_out, int out_size, void* d_ws, size_t ws_size,
                              hipStream_t stream) {
    (void)in_sizes; (void)n_in; (void)d_ws; (void)ws_size; (void)out_size;
    const float* x   = (const float*)d_in[0];
    const float* t   = (const float*)d_in[1];
    const float* fW1 = (const float*)d_in[2];
    const float* fb1 = (const float*)d_in[3];
    const float* fW2 = (const float*)d_in[4];
    const float* fb2 = (const float*)d_in[5];
    const float* fW3 = (const float*)d_in[6];
    const float* fb3 = (const float*)d_in[7];
    const float* gW1 = (const float*)d_in[8];
    const float* gb1 = (const float*)d_in[9];
    const float* gW2 = (const float*)d_in[10];
    const float* gb2 = (const float*)d_in[11];
    const float* gW3 = (const float*)d_in[12];
    const float* gb3 = (const float*)d_in[13];
    const float* iW1 = (const float*)d_in[14];
    const float* ib1 = (const float*)d_in[15];
    const float* iW2 = (const float*)d_in[16];
    const float* ib2 = (const float*)d_in[17];
    const float* iW3 = (const float*)d_in[18];
    const float* ib3 = (const float*)d_in[19];
    float* out = (float*)d_out;

    NeuralNet_37615323578557_kernel<<<dim3(2048), 256, 0, stream>>>(
        x, t, fW1, fb1, fW2, fb2, fW3, fb3,
        gW1, gb1, gW2, gb2, gW3, gb3,
        iW1, ib1, iW2, ib2, iW3, ib3, out);
}

// Round 5
// 272.142 us; speedup vs baseline: 2.8324x; 1.0863x over previous
//
#include <hip/hip_runtime.h>
#include <stdint.h>

typedef __attribute__((ext_vector_type(8))) short short8;
typedef __attribute__((ext_vector_type(4))) float floatx4;

#define MFMA16(a, b, c) __builtin_amdgcn_mfma_f32_16x16x32_bf16(a, b, c, 0, 0, 0)

// Pack two fp32 -> bf16 pair (lo, hi) in ONE v_perm_b32 after +0x8000
// round-half-up (vs software RNE: ~10 VALU -> 3 VALU per pair; error
// bounded by RNE + 2^-17 relative).
__device__ __forceinline__ unsigned pkbf(float lo, float hi) {
    const unsigned a = __builtin_bit_cast(unsigned, lo) + 0x8000u;
    const unsigned b = __builtin_bit_cast(unsigned, hi) + 0x8000u;
    return __builtin_amdgcn_perm(b, a, 0x07060302u);  // {b.hi16, a.hi16}
}
__device__ __forceinline__ unsigned short f2bf(float x) {
    unsigned u = __builtin_bit_cast(unsigned, x);
    u = (u + 0x7fffu + ((u >> 16) & 1u)) >> 16;  // RNE (cold paths only)
    return (unsigned short)u;
}

// Activation tiles are 64x128 bf16 viewed as u32 pairs: u32 index u of a row
// holds bf16 cols (2u, 2u+1). 16B chunks XOR-swizzled by row&15: b32 C-layout
// writes stay <=2-way (free), b128 A-frag reads are bank-balanced.
__device__ __forceinline__ int hphys(int row, int u) {
    return row * 64 + ((((u >> 2) ^ (row & 15)) << 2) | (u & 3));
}

// Grid: 2048 WGs; WG owns batch rows [2*bx, 2*bx+2) — fwd, bwd and init all
// accumulate in LDS (accT), one coalesced writeout, no global atomics.
// 64-row tiles (8 per dir): h1+h2 live in one 32 KB sbuf -> 37 KB LDS total
// -> 4 WGs/CU (vs 2 at 128-row tiles); waves_per_eu(4,4) pins VGPRs <= 128.
// N-split: wave w owns hidden cols [32w,32w+32) for layers 1-2 (W1/W2 B-frags
// in regs; even/odd col pairing -> packed b32 LDS writes). Layer 3 M-split
// (wave w owns rows [16w,16w+16)). W2 frags staged per-dir through sbuf
// (coalesced float4 load -> bf16 B-frag image -> 8 conflict-free
// ds_read_b128 per lane) to avoid the scattered-load pressure spike.
__global__ __launch_bounds__(256)
__attribute__((amdgpu_waves_per_eu(4, 4)))
void NeuralNet_37615323578557_kernel(
        const float* __restrict__ x, const float* __restrict__ t,
        const float* __restrict__ fW1, const float* __restrict__ fb1,
        const float* __restrict__ fW2, const float* __restrict__ fb2,
        const float* __restrict__ fW3, const float* __restrict__ fb3,
        const float* __restrict__ gW1, const float* __restrict__ gb1,
        const float* __restrict__ gW2, const float* __restrict__ gb2,
        const float* __restrict__ gW3, const float* __restrict__ gb3,
        const float* __restrict__ iW1, const float* __restrict__ ib1,
        const float* __restrict__ iW2, const float* __restrict__ ib2,
        const float* __restrict__ iW3, const float* __restrict__ ib3,
        float* __restrict__ out) {
    __shared__ unsigned sbuf[8192];             // 32 KB: h1 | h2 (or W2 image)
    __shared__ unsigned short fbuf[64 * 8];     // 1 KB feats / init scratch
    __shared__ float accT[2 * 256 * 2];         // 4 KB output accumulator

    unsigned* const h1buf = sbuf;               // 16 KB (64 rows x 64 u32)
    unsigned* const h2buf = sbuf + 4096;        // 16 KB

    const int tid  = threadIdx.x;
    const int lane = tid & 63;
    const int w    = tid >> 6;      // wave 0..3
    const int c    = lane & 15;     // MFMA low index (m for A, n for B/C)
    const int q    = lane >> 4;     // MFMA quad
    const int b0   = blockIdx.x * 2;

    // ---- zero the output accumulator ----
    #pragma unroll
    for (int k = 0; k < 4; ++k) accT[tid + k * 256] = 0.0f;
    __syncthreads();

    // ---- init MLP: waves 0,1 handle b_local = w (pure fp32 VALU) ----
    // Scratch = fbuf (512 B per wave, exactly 1 KB); sbuf stays free for the
    // dir-0 W2 staging other waves start concurrently.
    if (w < 2) {
        float* h1s = (float*)fbuf + w * 128;
        const int b = b0 + w;
        const float* xb = x + (size_t)b * 514;
        const float f0 = xb[0], f1 = xb[1], f2 = t[b];
        const int u0 = lane, u1 = lane + 64;
        const float h0 = fmaxf(iW1[u0] * f0 + iW1[128 + u0] * f1 + iW1[256 + u0] * f2 + ib1[u0], 0.f);
        const float h1 = fmaxf(iW1[u1] * f0 + iW1[128 + u1] * f1 + iW1[256 + u1] * f2 + ib1[u1], 0.f);
        h1s[u0] = h0;
        h1s[u1] = h1;
        float a0 = ib2[lane], a1 = ib2[lane + 64];
        for (int k = 0; k < 128; ++k) {
            const float hv = h1s[k];
            a0 += hv * iW2[k * 128 + lane];
            a1 += hv * iW2[k * 128 + lane + 64];
        }
        a0 = fmaxf(a0, 0.f); a1 = fmaxf(a1, 0.f);
        float p0 = a0 * iW3[lane * 2 + 0] + a1 * iW3[(lane + 64) * 2 + 0];
        float p1 = a0 * iW3[lane * 2 + 1] + a1 * iW3[(lane + 64) * 2 + 1];
        #pragma unroll
        for (int m = 1; m < 64; m <<= 1) {
            p0 += __shfl_xor(p0, m, 64);
            p1 += __shfl_xor(p1, m, 64);
        }
        if (lane == 0) {
            accT[w * 512 + 0] += p0 + ib3[0];
            accT[w * 512 + 1] += p1 + ib3[1];
        }
    }

    const int wbase = w * 32;
    const int ucol  = w * 16 + c;   // u32 col index this lane writes

    for (int dir = 0; dir < 2; ++dir) {
        const float* W1 = dir ? gW1 : fW1;
        const float* B1 = dir ? gb1 : fb1;
        const float* W2 = dir ? gW2 : fW2;
        const float* B2 = dir ? gb2 : fb2;
        const float* W3 = dir ? gW3 : fW3;
        const float* B3 = dir ? gb3 : fb3;

        __syncthreads();  // prev dir's sbuf reads / init fbuf use complete

        // ---- stage W2 B-frag image into sbuf (exactly 32 KB) ----
        // Element (k,n) -> block B=((n>>5)*2+(n&1))*4+(k>>5),
        //   ushort idx = B*512 + (((k>>3)&3)*16 + ((n>>1)&15))*8 + (k&7).
        // Thread stages rows {k0,k0+1} x cols [c0,c0+32): k-pair shares
        // ks/q2, adjacent j -> one packed b32 LDS write per n.
        {
            const int k0 = (tid >> 2) << 1;
            const int c0 = (tid & 3) << 5;
            const int ks = k0 >> 5;
            const int q2 = (k0 >> 3) & 3;
            const int j0 = k0 & 7;          // even
            const float* r0p = &W2[k0 * 128 + c0];
            const float* r1p = r0p + 128;
            #pragma unroll
            for (int nn = 0; nn < 32; nn += 4) {
                const float4 v0 = *(const float4*)(r0p + nn);
                const float4 v1 = *(const float4*)(r1p + nn);
                #pragma unroll
                for (int e = 0; e < 4; ++e) {
                    const int n = c0 + nn + e;
                    const unsigned pv = pkbf(((const float*)&v0)[e],
                                             ((const float*)&v1)[e]);
                    const int B = ((n >> 5) * 2 + (n & 1)) * 4 + ks;
                    const int us = B * 512 + (q2 * 16 + ((n >> 1) & 15)) * 8 + j0;
                    sbuf[us >> 1] = pv;
                }
            }
        }

        // ---- small weight frags (W1, W3, biases) straight to regs ----
        short8 w1f[2], w3f[4];
        float  b1v[2], b2v[2];
        #pragma unroll
        for (int ntl = 0; ntl < 2; ++ntl) {
            const int col = wbase + 2 * c + ntl;
            b1v[ntl] = B1[col];
            b2v[ntl] = B2[col];
            short8 f = {0, 0, 0, 0, 0, 0, 0, 0};
            if (q == 0) {  // K padded 8 -> 32: only quad 0 holds real W1 rows
                #pragma unroll
                for (int j = 0; j < 8; ++j) f[j] = (short)f2bf(W1[j * 128 + col]);
            }
            w1f[ntl] = f;
        }
        const float b3c = (c < 2) ? B3[c] : 0.0f;
        #pragma unroll
        for (int ks = 0; ks < 4; ++ks) {  // W3: N padded 2 -> 16
            short8 f = {0, 0, 0, 0, 0, 0, 0, 0};
            if (c < 2) {
                #pragma unroll
                for (int j = 0; j < 8; ++j)
                    f[j] = (short)f2bf(W3[(ks * 32 + q * 8 + j) * 2 + c]);
            }
            w3f[ks] = f;
        }
        __syncthreads();  // W2 frag image complete

        // ---- w2f from LDS: 8 conflict-free ds_read_b128 per lane ----
        short8 w2f[2][4];
        {
            const unsigned short* img = (const unsigned short*)sbuf;
            #pragma unroll
            for (int ntl = 0; ntl < 2; ++ntl)
                #pragma unroll
                for (int ks = 0; ks < 4; ++ks)
                    w2f[ntl][ks] = *(const short8*)
                        &img[(((w * 2 + ntl) * 4 + ks) << 9) + lane * 8];
        }
        // (w2f reads complete before the feats barrier below -> sbuf safe to
        //  overwrite with h1 after that barrier)

        for (int tt = 0; tt < 8; ++tt) {
            const int r0 = tt * 64;

            // ---- stage features: row r -> (b_local=r/255, i=r%255) ----
            if (tid < 64) {
                const int r = r0 + tid;
                unsigned v0 = 0, v1 = 0, v2 = 0, v3 = 0;
                if (r < 510) {
                    const int bl = r / 255;
                    const int i  = r - bl * 255;
                    const float* xb = x + (size_t)(b0 + bl) * 514;
                    const float2 xi  = *(const float2*)(xb + 2 * i);
                    const float2 xi1 = *(const float2*)(xb + 2 * i + 2);
                    const float2 pt  = *(const float2*)(xb + 512);   // x[b,T,:]
                    const float tv = t[b0 + bl];
                    const float nv = (float)(dir ? i : (i + 1)) * (1.0f / 256.0f);
                    if (dir == 0) {  // [x_{i+1}, t, x_i, (i+1)/T, pt]
                        v0 = pkbf(xi1.x, xi1.y);
                        v1 = pkbf(tv, xi.x);
                        v2 = pkbf(xi.y, nv);
                    } else {         // [x_i, t, x_{i+1}, i/T, pt]
                        v0 = pkbf(xi.x, xi.y);
                        v1 = pkbf(tv, xi1.x);
                        v2 = pkbf(xi1.y, nv);
                    }
                    v3 = pkbf(pt.x, pt.y);
                }
                unsigned* fp = (unsigned*)&fbuf[tid * 8];
                fp[0] = v0; fp[1] = v1; fp[2] = v2; fp[3] = v3;
            }
            __syncthreads();  // feats ready; w2f reads drained

            // ---- layer 1: h1[cols wbase..wbase+32) for 64 rows ----
            #pragma unroll
            for (int mt = 0; mt < 4; ++mt) {
                short8 af = {0, 0, 0, 0, 0, 0, 0, 0};
                if (q == 0) af = *(const short8*)&fbuf[(mt * 16 + c) * 8];
                floatx4 a0 = {b1v[0], b1v[0], b1v[0], b1v[0]};
                floatx4 a1 = {b1v[1], b1v[1], b1v[1], b1v[1]};
                a0 = MFMA16(af, w1f[0], a0);
                a1 = MFMA16(af, w1f[1], a1);
                const int rowb = mt * 16 + q * 4;
                #pragma unroll
                for (int rr = 0; rr < 4; ++rr)
                    h1buf[hphys(rowb + rr, ucol)] =
                        pkbf(fmaxf(a0[rr], 0.0f), fmaxf(a1[rr], 0.0f));
            }
            __syncthreads();  // h1 complete

            // ---- layer 2: read h1, write h2 (disjoint halves) ----
            #pragma unroll
            for (int mt = 0; mt < 4; ++mt) {
                const int row = mt * 16 + c;
                const int sw  = row & 15;
                const unsigned* rp = &h1buf[row * 64];
                short8 a0 = *(const short8*)&rp[(((0 + q) ^ sw) << 2)];
                short8 a1 = *(const short8*)&rp[(((4 + q) ^ sw) << 2)];
                short8 a2 = *(const short8*)&rp[(((8 + q) ^ sw) << 2)];
                short8 a3 = *(const short8*)&rp[(((12 + q) ^ sw) << 2)];
                floatx4 s0 = {b2v[0], b2v[0], b2v[0], b2v[0]};
                floatx4 s1 = {b2v[1], b2v[1], b2v[1], b2v[1]};
                s0 = MFMA16(a0, w2f[0][0], s0); s1 = MFMA16(a0, w2f[1][0], s1);
                s0 = MFMA16(a1, w2f[0][1], s0); s1 = MFMA16(a1, w2f[1][1], s1);
                s0 = MFMA16(a2, w2f[0][2], s0); s1 = MFMA16(a2, w2f[1][2], s1);
                s0 = MFMA16(a3, w2f[0][3], s0); s1 = MFMA16(a3, w2f[1][3], s1);
                const int rowb = mt * 16 + q * 4;
                #pragma unroll
                for (int rr = 0; rr < 4; ++rr)
                    h2buf[hphys(rowb + rr, ucol)] =
                        pkbf(fmaxf(s0[rr], 0.0f), fmaxf(s1[rr], 0.0f));
            }
            __syncthreads();  // h2 complete

            // ---- layer 3: wave owns rows [16w,16w+16); add into accT ----
            {
                const int row = w * 16 + c;
                const int sw  = row & 15;
                const unsigned* rp = &h2buf[row * 64];
                short8 a0 = *(const short8*)&rp[(((0 + q) ^ sw) << 2)];
                short8 a1 = *(const short8*)&rp[(((4 + q) ^ sw) << 2)];
                short8 a2 = *(const short8*)&rp[(((8 + q) ^ sw) << 2)];
                short8 a3 = *(const short8*)&rp[(((12 + q) ^ sw) << 2)];
                floatx4 s = {b3c, b3c, b3c, b3c};
                s = MFMA16(a0, w3f[0], s);
                s = MFMA16(a1, w3f[1], s);
                s = MFMA16(a2, w3f[2], s);
                s = MFMA16(a3, w3f[3], s);
                if (c < 2) {
                    const int rowb = w * 16 + q * 4;
                    #pragma unroll
                    for (int rr = 0; rr < 4; ++rr) {
                        const int r = r0 + rowb + rr;
                        if (r < 510) {
                            const int bl = r / 255;
                            const int i  = r - bl * 255;
                            const int pos = i + 1 - dir;
                            accT[(bl << 9) + pos * 2 + c] += s[rr];
                        }
                    }
                }
            }
            // next tile's h1/h2 writes ordered by its own barriers
        }
    }

    __syncthreads();  // accT complete
    // ---- coalesced writeout: 1024 floats = out[b0..b0+1] ----
    ((float4*)(out + (size_t)b0 * 512))[tid] = ((const float4*)accT)[tid];
}

extern "C" void kernel_launch(void* const* d_in, const int* in_sizes, int n_in,
                              void* d_out, int out_size, void* d_ws, size_t ws_size,
                              hipStream_t stream) {
    (void)in_sizes; (void)n_in; (void)d_ws; (void)ws_size; (void)out_size;
    const float* x   = (const float*)d_in[0];
    const float* t   = (const float*)d_in[1];
    const float* fW1 = (const float*)d_in[2];
    const float* fb1 = (const float*)d_in[3];
    const float* fW2 = (const float*)d_in[4];
    const float* fb2 = (const float*)d_in[5];
    const float* fW3 = (const float*)d_in[6];
    const float* fb3 = (const float*)d_in[7];
    const float* gW1 = (const float*)d_in[8];
    const float* gb1 = (const float*)d_in[9];
    const float* gW2 = (const float*)d_in[10];
    const float* gb2 = (const float*)d_in[11];
    const float* gW3 = (const float*)d_in[12];
    const float* gb3 = (const float*)d_in[13];
    const float* iW1 = (const float*)d_in[14];
    const float* ib1 = (const float*)d_in[15];
    const float* iW2 = (const float*)d_in[16];
    const float* ib2 = (const float*)d_in[17];
    const float* iW3 = (const float*)d_in[18];
    const float* ib3 = (const float*)d_in[19];
    float* out = (float*)d_out;

    NeuralNet_37615323578557_kernel<<<dim3(2048), 256, 0, stream>>>(
        x, t, fW1, fb1, fW2, fb2, fW3, fb3,
        gW1, gb1, gW2, gb2, gW3, gb3,
        iW1, ib1, iW2, ib2, iW3, ib3, out);
}